// Round 3
// baseline (142.807 us; speedup 1.0000x reference)
//
#include <hip/hip_runtime.h>
#include <hip/hip_bf16.h>

// ConvolutionalAttention2D: B=16, C=256, N=H*W=4096.
// out = (Wo * (phiQ @ phiV^T)) @ phiK + bo, phiX = elu(Wx @ x)+1
// bf16 MFMA (16x16x32), fp32 accumulate.
// K=256 GEMMs: A-fragments resident in VGPRs, B streamed via global_load_lds
// with XOR swizzle, double-buffered, ONE barrier per 64-k step.

typedef short  bf16x8 __attribute__((ext_vector_type(8)));
typedef float  f32x4  __attribute__((ext_vector_type(4)));
typedef unsigned short u16x4 __attribute__((ext_vector_type(4)));

#define NB 16
#define NC 256
#define NN 4096

__device__ __forceinline__ unsigned short f2bf(float f) {
    union { float f; unsigned u; } v; v.f = f;
    unsigned r = v.u + 0x7FFFu + ((v.u >> 16) & 1u);
    return (unsigned short)(r >> 16);
}

__device__ __forceinline__ float phi_act(float v) {
    return v > 0.f ? v + 1.f : __expf(v);
}

__device__ __forceinline__ void gload_lds16(const void* g, void* l) {
    __builtin_amdgcn_global_load_lds(
        (const __attribute__((address_space(1))) void*)g,
        (__attribute__((address_space(3))) void*)l, 16, 0, 0);
}

// Stage a 128row x 64k bf16 tile (16 KB) into linear LDS with XOR-swizzled
// SOURCE address (both-sides swizzle; reads use frag_ld's matching XOR).
__device__ __forceinline__ void stage_tile(
    const unsigned short* __restrict__ src, int ld, int kb, char* lds, int t)
{
    const int kslot  = t & 7;
    const int rbase  = t >> 3;                         // 0..31
    const int srcOff = (kslot * 16) ^ ((rbase & 7) << 4);
    const int wbase  = (t >> 6) * 1024;                // wave-uniform
    #pragma unroll
    for (int i = 0; i < 4; ++i) {
        const int r = i * 32 + rbase;
        const char* g = (const char*)(src + (size_t)r * ld + kb) + srcOff;
        gload_lds16(g, lds + i * 4096 + wbase);
    }
}

// Swizzled fragment read: row-major [128][64] bf16, byte ^= ((row&7)<<4)
__device__ __forceinline__ bf16x8 frag_ld(const char* lds, int row, int kbyte) {
    return *(const bf16x8*)(lds + row * 128 + (kbyte ^ ((row & 7) << 4)));
}

// ---------------------------------------------------------------------------
// K=256 engine, A-fragments in registers. Block = 4 waves, 128x128 out tile,
// G consecutive 128-wide n-tiles. One __syncthreads per 64-k step.
// SWAP=false: acc[m][n] rows = A-dim (wr+m*16+q4+i), cols = B-dim (wc+n*16+c15)
// SWAP=true : acc[m][n] rows = B-dim (wc+n*16+q4+i), cols = A-dim (wr+m*16+c15)
// ---------------------------------------------------------------------------
template<bool SWAP, int G, class Epi>
__device__ __forceinline__ void gemm_k256_regA(
    const unsigned short* __restrict__ A,        // [128][256] slab, lda=256
    const unsigned short* __restrict__ BT0, int ldb,
    char* lds, Epi epi)
{
    const int t = threadIdx.x, lane = t & 63, w = t >> 6;
    const int wr = (w >> 1) * 64, wc = (w & 1) * 64;
    const int q = lane >> 4, c15 = lane & 15;

    // preload A fragments: row = wr+m*16+c15, k = kg*32 + q*8
    bf16x8 af[8][4];
    {
        const unsigned short* ab = A + (size_t)(wr + c15) * NC + q * 8;
        #pragma unroll
        for (int kg = 0; kg < 8; ++kg)
            #pragma unroll
            for (int m = 0; m < 4; ++m)
                af[kg][m] = *(const bf16x8*)(ab + m * 16 * NC + kg * 32);
    }

    stage_tile(BT0, ldb, 0, lds, t);           // buf0 <- (nti=0, kt=0)
    f32x4 acc[4][4] = {};
    for (int nti = 0; nti < G; ++nti) {
        const unsigned short* BT = BT0 + (size_t)nti * 128 * ldb;
        #pragma unroll
        for (int kt = 0; kt < 4; ++kt) {
            __syncthreads();                   // staged data ready; prior reads done
            if (kt < 3)
                stage_tile(BT, ldb, (kt + 1) * 64, lds + ((kt + 1) & 1) * 16384, t);
            else if (nti + 1 < G)
                stage_tile(BT + 128 * ldb, ldb, 0, lds + ((kt + 1) & 1) * 16384, t);
            const char* cur = lds + (kt & 1) * 16384;
            #pragma unroll
            for (int g = 0; g < 2; ++g) {
                bf16x8 bfr[4];
                #pragma unroll
                for (int n = 0; n < 4; ++n)
                    bfr[n] = frag_ld(cur, wc + n * 16 + c15, g * 64 + q * 16);
                #pragma unroll
                for (int m = 0; m < 4; ++m)
                    #pragma unroll
                    for (int n = 0; n < 4; ++n)
                        acc[m][n] = SWAP
                            ? __builtin_amdgcn_mfma_f32_16x16x32_bf16(bfr[n], af[kt * 2 + g][m], acc[m][n], 0, 0, 0)
                            : __builtin_amdgcn_mfma_f32_16x16x32_bf16(af[kt * 2 + g][m], bfr[n], acc[m][n], 0, 0, 0);
            }
            if (kt == 3) {
                epi(nti, acc);
                #pragma unroll
                for (int m = 0; m < 4; ++m)
                    #pragma unroll
                    for (int n = 0; n < 4; ++n)
                        acc[m][n] = f32x4{0.f, 0.f, 0.f, 0.f};
            }
        }
    }
}

// ---------------------------------------------------------------------------
// Deep-K engine (k_qv): both operands staged, double-buffered, 1 barrier/step.
// LDS layout: [A0 16K][B0 16K][A1 16K][B1 16K] = 64 KB.
// ---------------------------------------------------------------------------
template<bool SWAP>
__device__ __forceinline__ void gemm128_db(
    const unsigned short* __restrict__ A, int lda,
    const unsigned short* __restrict__ BT, int ldb,
    int k0, int nk, char* lds, f32x4 (&acc)[4][4])
{
    const int t = threadIdx.x, lane = t & 63, w = t >> 6;
    const int wr = (w >> 1) * 64, wc = (w & 1) * 64;
    const int q = lane >> 4, c15 = lane & 15;

    stage_tile(A,  lda, k0, lds, t);
    stage_tile(BT, ldb, k0, lds + 16384, t);
    for (int kt = 0; kt < nk; ++kt) {
        __syncthreads();
        if (kt + 1 < nk) {
            char* nxt = lds + ((kt + 1) & 1) * 32768;
            stage_tile(A,  lda, k0 + (kt + 1) * 64, nxt, t);
            stage_tile(BT, ldb, k0 + (kt + 1) * 64, nxt + 16384, t);
        }
        const char* cur = lds + (kt & 1) * 32768;
        #pragma unroll
        for (int g = 0; g < 2; ++g) {
            const int kbyte = g * 64 + q * 16;
            bf16x8 af[4], bfr[4];
            #pragma unroll
            for (int m = 0; m < 4; ++m) af[m]  = frag_ld(cur,         wr + m * 16 + c15, kbyte);
            #pragma unroll
            for (int n = 0; n < 4; ++n) bfr[n] = frag_ld(cur + 16384, wc + n * 16 + c15, kbyte);
            #pragma unroll
            for (int m = 0; m < 4; ++m)
                #pragma unroll
                for (int n = 0; n < 4; ++n)
                    acc[m][n] = SWAP
                        ? __builtin_amdgcn_mfma_f32_16x16x32_bf16(bfr[n], af[m], acc[m][n], 0, 0, 0)
                        : __builtin_amdgcn_mfma_f32_16x16x32_bf16(af[m], bfr[n], acc[m][n], 0, 0, 0);
        }
    }
}

// --------------------------- K0a: weights -> bf16 ---------------------------
__global__ __launch_bounds__(256) void k_wconv(
    const float* __restrict__ Wq, const float* __restrict__ Wk,
    const float* __restrict__ Wv, const float* __restrict__ Wo,
    unsigned short* __restrict__ Wqkv, unsigned short* __restrict__ Wob)
{
    int i = blockIdx.x * 256 + threadIdx.x;        // 262144 total
    if      (i < 65536)  Wqkv[i] = f2bf(Wq[i]);
    else if (i < 131072) Wqkv[i] = f2bf(Wk[i - 65536]);
    else if (i < 196608) Wqkv[i] = f2bf(Wv[i - 131072]);
    else if (i < 262144) Wob[i - 196608] = f2bf(Wo[i - 196608]);
}

// ------------------- K0b: x[b][c][n] f32 -> xT[b][n][c] bf16 ----------------
__global__ __launch_bounds__(256) void k_xpose(
    const float* __restrict__ x, unsigned short* __restrict__ xT)
{
    __shared__ float tile[64][68];
    const int b  = blockIdx.z;
    const int n0 = blockIdx.x * 64, c0 = blockIdx.y * 64;
    const int t  = threadIdx.x;
    const float* xp = x + ((size_t)b * NC + c0) * NN + n0;
    const int cc = t >> 4, nq = t & 15;
    #pragma unroll
    for (int j = 0; j < 4; ++j) {
        const int c = j * 16 + cc;
        f32x4 v = *(const f32x4*)(xp + (size_t)c * NN + nq * 4);
        *(f32x4*)&tile[c][nq * 4] = v;
    }
    __syncthreads();
    unsigned short* op = xT + ((size_t)b * NN + n0) * NC + c0;
    const int nn0 = t >> 4, cq = t & 15;
    #pragma unroll
    for (int j = 0; j < 4; ++j) {
        const int nn = j * 16 + nn0;
        u16x4 o;
        #pragma unroll
        for (int ii = 0; ii < 4; ++ii) o[ii] = f2bf(tile[cq * 4 + ii][nn]);
        *(u16x4*)(op + (size_t)nn * NC + cq * 4) = o;
    }
}

// ------ K1a: phiQ/phiV [c][n] = phi(W @ x); SWAP epilogue; G=4 --------------
__global__ __launch_bounds__(256, 2) void k_projQV(
    const unsigned short* __restrict__ Wqkv, const unsigned short* __restrict__ xT,
    unsigned short* __restrict__ phiQ, unsigned short* __restrict__ phiV)
{
    __shared__ __align__(16) char lds[32768];
    const int bid = blockIdx.x;                    // 512 = 16b * 4slab * 8ntg
    const int ntg = bid & 7, sq = (bid >> 3) & 3, b = bid >> 5;
    const int mt  = (sq < 2) ? sq : sq + 2;        // Q slabs 0,1; V slabs 4,5
    const unsigned short* A   = Wqkv + (size_t)mt * 128 * NC;
    const unsigned short* BT0 = xT + ((size_t)b * NN + ntg * 512) * NC;
    unsigned short* dst = (sq < 2 ? phiQ : phiV) + (size_t)b * NC * NN;

    const int lane = threadIdx.x & 63, w = threadIdx.x >> 6;
    const int wr = (w >> 1) * 64, wc = (w & 1) * 64;
    const int q4 = ((lane >> 4) & 3) * 4, c15 = lane & 15;
    const int ob = (sq & 1) * 128 + wr + c15;

    gemm_k256_regA<true, 4>(A, BT0, NC, lds,
        [&](int nti, f32x4 (&acc)[4][4]) {
            const int nb = ntg * 512 + nti * 128 + wc + q4;
            #pragma unroll
            for (int m = 0; m < 4; ++m)
                #pragma unroll
                for (int n = 0; n < 4; ++n) {
                    u16x4 pk;
                    #pragma unroll
                    for (int i = 0; i < 4; ++i) pk[i] = f2bf(phi_act(acc[m][n][i]));
                    *(u16x4*)(dst + (size_t)(ob + m * 16) * NN + nb + n * 16) = pk;
                }
        });
}

// ------ K1b: phiKT [n][c] = phi(Wk @ x); no-swap epilogue; G=2 --------------
__global__ __launch_bounds__(256, 2) void k_projK(
    const unsigned short* __restrict__ Wqkv, const unsigned short* __restrict__ xT,
    unsigned short* __restrict__ phiKT)
{
    __shared__ __align__(16) char lds[32768];
    const int bid = blockIdx.x;                    // 512 = 16b * 2slab * 16ntg
    const int ntg = bid & 15, sk = (bid >> 4) & 1, b = bid >> 5;
    const unsigned short* A   = Wqkv + (size_t)(2 + sk) * 128 * NC;
    const unsigned short* BT0 = xT + ((size_t)b * NN + ntg * 256) * NC;
    unsigned short* dst = phiKT + (size_t)b * NN * NC;

    const int lane = threadIdx.x & 63, w = threadIdx.x >> 6;
    const int wr = (w >> 1) * 64, wc = (w & 1) * 64;
    const int q4 = ((lane >> 4) & 3) * 4, c15 = lane & 15;
    const int cb = sk * 128 + wr + q4;

    gemm_k256_regA<false, 2>(A, BT0, NC, lds,
        [&](int nti, f32x4 (&acc)[4][4]) {
            const int nb = ntg * 256 + nti * 128 + wc + c15;
            #pragma unroll
            for (int m = 0; m < 4; ++m)
                #pragma unroll
                for (int n = 0; n < 4; ++n) {
                    u16x4 pk;
                    #pragma unroll
                    for (int i = 0; i < 4; ++i) pk[i] = f2bf(phi_act(acc[m][n][i]));
                    *(u16x4*)(dst + (size_t)(nb + n * 16) * NC + cb + m * 16) = pk;
                }
        });
}

// ------ K2: qvT_part[s][b][d][c] partials, split-K=8 ------------------------
__global__ __launch_bounds__(256, 2) void k_qv(
    const unsigned short* __restrict__ phiQ, const unsigned short* __restrict__ phiV,
    float* __restrict__ qvTp)
{
    __shared__ __align__(16) char lds[65536];
    const int bid = blockIdx.x;                    // 512 blocks
    const int s = bid & 7, nt = (bid >> 3) & 1, mt = (bid >> 4) & 1, b = bid >> 5;
    const unsigned short* A  = phiQ + ((size_t)b * NC + mt * 128) * NN;
    const unsigned short* BT = phiV + ((size_t)b * NC + nt * 128) * NN;
    f32x4 acc[4][4] = {};
    gemm128_db<false>(A, NN, BT, NN, s * 512, 8, lds, acc);

    const int lane = threadIdx.x & 63, w = threadIdx.x >> 6;
    const int wr = (w >> 1) * 64, wc = (w & 1) * 64;
    const int q4 = (lane >> 4) * 4, c15 = lane & 15;
    float* dst = qvTp + (((size_t)s * NB + b) << 16);
    const int c0 = mt * 128 + wr + q4;
    const int d0 = nt * 128 + wc + c15;
    #pragma unroll
    for (int m = 0; m < 4; ++m)
        #pragma unroll
        for (int n = 0; n < 4; ++n)
            *(f32x4*)(dst + (size_t)(d0 + n * 16) * NC + c0 + m * 16) = acc[m][n];
}

// ------ K2b: qvT[b][d][c] bf16 = sum_s partials -----------------------------
__global__ __launch_bounds__(256) void k_qvred(
    const float* __restrict__ p, unsigned short* __restrict__ qvT)
{
    const size_t i = (size_t)blockIdx.x * 256 + threadIdx.x;  // 262144 f32x4 units
    const f32x4* pv = (const f32x4*)p;
    f32x4 v = pv[i];
    #pragma unroll
    for (int s = 1; s < 8; ++s) v = v + pv[i + (size_t)s * 262144];
    u16x4 o;
    #pragma unroll
    for (int j = 0; j < 4; ++j) o[j] = f2bf(v[j]);
    ((u16x4*)qvT)[i] = o;
}

// ------ K3: Mb[b][o][d] = Wo @ qv  (SWAP: regs span d) -----------------------
__global__ __launch_bounds__(256, 2) void k_mproj(
    const unsigned short* __restrict__ Wob, const unsigned short* __restrict__ qvT,
    unsigned short* __restrict__ Mb)
{
    __shared__ __align__(16) char lds[32768];
    const int bid = blockIdx.x;                    // 64 blocks
    const int nt = bid & 1, mt = (bid >> 1) & 1, b = bid >> 2;
    const unsigned short* A   = Wob + (size_t)mt * 128 * NC;
    const unsigned short* BT0 = qvT + ((size_t)b << 16) + (size_t)nt * 128 * NC;
    unsigned short* dst = Mb + ((size_t)b << 16);

    const int lane = threadIdx.x & 63, w = threadIdx.x >> 6;
    const int wr = (w >> 1) * 64, wc = (w & 1) * 64;
    const int q4 = ((lane >> 4) & 3) * 4, c15 = lane & 15;
    const int ob = mt * 128 + wr + c15;
    const int db = nt * 128 + wc + q4;

    gemm_k256_regA<true, 1>(A, BT0, NC, lds,
        [&](int, f32x4 (&acc)[4][4]) {
            #pragma unroll
            for (int m = 0; m < 4; ++m)
                #pragma unroll
                for (int n = 0; n < 4; ++n) {
                    u16x4 pk;
                    #pragma unroll
                    for (int i = 0; i < 4; ++i) pk[i] = f2bf(acc[m][n][i]);
                    *(u16x4*)(dst + (size_t)(ob + m * 16) * NC + db + n * 16) = pk;
                }
        });
}

// ------ K4: out[b][o][n] = Mb @ phiK + bo  (SWAP; f32x4 stores); G=2 ---------
__global__ __launch_bounds__(256, 2) void k_out(
    const unsigned short* __restrict__ Mb, const unsigned short* __restrict__ phiKT,
    const float* __restrict__ bo, float* __restrict__ out)
{
    __shared__ __align__(16) char lds[32768];
    const int bid = blockIdx.x;                    // 512 = 16b * 2mt * 16ntg
    const int ntg = bid & 15, mt = (bid >> 4) & 1, b = bid >> 5;
    const unsigned short* A   = Mb + ((size_t)b << 16) + (size_t)mt * 128 * NC;
    const unsigned short* BT0 = phiKT + (size_t)b * NN * NC + (size_t)ntg * 256 * NC;
    float* dst = out + (size_t)b * NC * NN;

    const int lane = threadIdx.x & 63, w = threadIdx.x >> 6;
    const int wr = (w >> 1) * 64, wc = (w & 1) * 64;
    const int q4 = ((lane >> 4) & 3) * 4, c15 = lane & 15;

    gemm_k256_regA<true, 2>(A, BT0, NC, lds,
        [&](int nti, f32x4 (&acc)[4][4]) {
            #pragma unroll
            for (int m = 0; m < 4; ++m) {
                const int o = mt * 128 + wr + m * 16 + c15;
                const float bb = bo[o];
                #pragma unroll
                for (int n = 0; n < 4; ++n) {
                    f32x4 v = acc[m][n];
                    #pragma unroll
                    for (int i = 0; i < 4; ++i) v[i] += bb;
                    *(f32x4*)(dst + (size_t)o * NN + ntg * 256 + nti * 128 + wc + n * 16 + q4) = v;
                }
            }
        });
}

// ---------------------------------------------------------------------------
extern "C" void kernel_launch(void* const* d_in, const int* in_sizes, int n_in,
                              void* d_out, int out_size, void* d_ws, size_t ws_size,
                              hipStream_t stream)
{
    (void)in_sizes; (void)n_in; (void)out_size; (void)ws_size;
    const float* x  = (const float*)d_in[0];
    const float* Wq = (const float*)d_in[1];
    const float* Wk = (const float*)d_in[2];
    const float* Wv = (const float*)d_in[3];
    const float* Wo = (const float*)d_in[4];
    const float* bo = (const float*)d_in[5];
    float* out = (float*)d_out;

    char* ws = (char*)d_ws;
    size_t off = 0;
    auto alloc = [&](size_t bytes) {
        void* p = ws + off;
        off += (bytes + 255) & ~(size_t)255;
        return p;
    };
    unsigned short* xT    = (unsigned short*)alloc((size_t)NB * NN * NC * 2); // 32 MiB
    unsigned short* phiQ  = (unsigned short*)alloc((size_t)NB * NC * NN * 2); // 32 MiB
    unsigned short* phiV  = (unsigned short*)alloc((size_t)NB * NC * NN * 2); // 32 MiB
    unsigned short* phiKT = (unsigned short*)alloc((size_t)NB * NN * NC * 2); // 32 MiB
    unsigned short* qvT   = (unsigned short*)alloc((size_t)NB * NC * NC * 2); //  2 MiB
    unsigned short* Mb    = (unsigned short*)alloc((size_t)NB * NC * NC * 2); //  2 MiB
    unsigned short* Wqkv  = (unsigned short*)alloc((size_t)768 * NC * 2);
    unsigned short* Wob   = (unsigned short*)alloc((size_t)NC * NC * 2);
    float* qvTp = (float*)xT;   // alias: xT dead after k_proj*; 8*16*64K*4B = 32 MiB

    k_wconv<<<1024, 256, 0, stream>>>(Wq, Wk, Wv, Wo, Wqkv, Wob);
    k_xpose<<<dim3(NN / 64, NC / 64, NB), dim3(256), 0, stream>>>(x, xT);
    k_projQV<<<512, 256, 0, stream>>>(Wqkv, xT, phiQ, phiV);
    k_projK<<<512, 256, 0, stream>>>(Wqkv, xT, phiKT);
    k_qv<<<512, 256, 0, stream>>>(phiQ, phiV, qvTp);
    k_qvred<<<1024, 256, 0, stream>>>(qvTp, qvT);
    k_mproj<<<64, 256, 0, stream>>>(Wob, qvT, Mb);
    k_out<<<512, 256, 0, stream>>>(Mb, phiKT, bo, out);
}

// Round 4
// 124.146 us; speedup vs baseline: 1.1503x; 1.1503x over previous
//
#include <hip/hip_runtime.h>
#include <hip/hip_bf16.h>

// ConvolutionalAttention2D: B=16, C=256, N=H*W=4096.
// out = (Wo * (phiQ @ phiV^T)) @ phiK + bo, phiX = elu(Wx @ x)+1
// bf16 MFMA (16x16x32), fp32 accumulate, global_load_lds staging + XOR swizzle.
// Round 4: round-2 engine (known good) + XCD chunk swizzle + fused preprocessing.

typedef short  bf16x8 __attribute__((ext_vector_type(8)));
typedef float  f32x4  __attribute__((ext_vector_type(4)));
typedef unsigned short u16x4 __attribute__((ext_vector_type(4)));

#define NB 16
#define NC 256
#define NN 4096

__device__ __forceinline__ unsigned short f2bf(float f) {
    union { float f; unsigned u; } v; v.f = f;
    unsigned r = v.u + 0x7FFFu + ((v.u >> 16) & 1u);
    return (unsigned short)(r >> 16);
}

__device__ __forceinline__ float phi_act(float v) {
    return v > 0.f ? v + 1.f : __expf(v);
}

__device__ __forceinline__ void gload_lds16(const void* g, void* l) {
    __builtin_amdgcn_global_load_lds(
        (const __attribute__((address_space(1))) void*)g,
        (__attribute__((address_space(3))) void*)l, 16, 0, 0);
}

// Stage a 128row x 64k bf16 tile (16 KB) into linear LDS with XOR-swizzled
// SOURCE address (both-sides swizzle; reads use frag_ld's matching XOR).
__device__ __forceinline__ void stage_tile(
    const unsigned short* __restrict__ src, int ld, int kb, char* lds, int t)
{
    const int kslot  = t & 7;
    const int rbase  = t >> 3;                         // 0..31
    const int srcOff = (kslot * 16) ^ ((rbase & 7) << 4);
    const int wbase  = (t >> 6) * 1024;                // wave-uniform
    #pragma unroll
    for (int i = 0; i < 4; ++i) {
        const int r = i * 32 + rbase;
        const char* g = (const char*)(src + (size_t)r * ld + kb) + srcOff;
        gload_lds16(g, lds + i * 4096 + wbase);
    }
}

// Swizzled fragment read: row-major [128][64] bf16, byte ^= ((row&7)<<4)
__device__ __forceinline__ bf16x8 frag_ld(const char* lds, int row, int kbyte) {
    return *(const bf16x8*)(lds + row * 128 + (kbyte ^ ((row & 7) << 4)));
}

// 128x128 NT GEMM tile: D[r][c] = sum_k A[r][k]*BT[c][k], k in [k0,k0+64*nk)
// 4 waves; wave w: (wr,wc) = ((w>>1)*64,(w&1)*64); frag grid 4x4 of 16x16.
// SWAP=false: acc[m][n] rows = A-dir (wr+m*16+q4+i), cols = B-dir (wc+n*16+c15)
// SWAP=true : acc[m][n] rows = B-dir (wc+n*16+q4+i), cols = A-dir (wr+m*16+c15)
template<bool SWAP>
__device__ __forceinline__ void gemm128(
    const unsigned short* __restrict__ A, int lda,
    const unsigned short* __restrict__ BT, int ldb,
    int k0, int nk, char* lsA, char* lsB, f32x4 (&acc)[4][4])
{
    const int t = threadIdx.x;
    const int lane = t & 63;
    const int w  = t >> 6;
    const int wr = (w >> 1) * 64, wc = (w & 1) * 64;
    const int q  = lane >> 4, c15 = lane & 15;

    for (int kt = 0; kt < nk; ++kt) {
        const int kb = k0 + kt * 64;
        if (kt) __syncthreads();            // prior reads done before overwrite
        stage_tile(A,  lda, kb, lsA, t);
        stage_tile(BT, ldb, kb, lsB, t);
        __syncthreads();                    // compiler drains vmcnt before barrier
        #pragma unroll
        for (int g = 0; g < 2; ++g) {
            const int kbyte = g * 64 + q * 16;
            bf16x8 af[4], bfr[4];
            #pragma unroll
            for (int m = 0; m < 4; ++m) af[m]  = frag_ld(lsA, wr + m * 16 + c15, kbyte);
            #pragma unroll
            for (int n = 0; n < 4; ++n) bfr[n] = frag_ld(lsB, wc + n * 16 + c15, kbyte);
            #pragma unroll
            for (int m = 0; m < 4; ++m)
                #pragma unroll
                for (int n = 0; n < 4; ++n)
                    acc[m][n] = SWAP
                        ? __builtin_amdgcn_mfma_f32_16x16x32_bf16(bfr[n], af[m], acc[m][n], 0, 0, 0)
                        : __builtin_amdgcn_mfma_f32_16x16x32_bf16(af[m], bfr[n], acc[m][n], 0, 0, 0);
        }
    }
}

// ---- K0 (fused): xpose (blocks 0..4095) + weight convert (blocks 4096..5119)
__global__ __launch_bounds__(256) void k_pre(
    const float* __restrict__ x,
    const float* __restrict__ Wq, const float* __restrict__ Wk,
    const float* __restrict__ Wv, const float* __restrict__ Wo,
    unsigned short* __restrict__ xT,
    unsigned short* __restrict__ Wqkv, unsigned short* __restrict__ Wob)
{
    __shared__ float tile[64][68];
    const int id = blockIdx.x;
    if (id >= 4096) {
        int i = (id - 4096) * 256 + threadIdx.x;   // 262144 total
        if      (i < 65536)  Wqkv[i] = f2bf(Wq[i]);
        else if (i < 131072) Wqkv[i] = f2bf(Wk[i - 65536]);
        else if (i < 196608) Wqkv[i] = f2bf(Wv[i - 131072]);
        else                 Wob[i - 196608] = f2bf(Wo[i - 196608]);
        return;
    }
    const int b  = id >> 8;
    const int n0 = (id & 63) * 64, c0 = ((id >> 6) & 3) * 64;
    const int t  = threadIdx.x;
    const float* xp = x + ((size_t)b * NC + c0) * NN + n0;
    const int cc = t >> 4, nq = t & 15;
    #pragma unroll
    for (int j = 0; j < 4; ++j) {
        const int c = j * 16 + cc;
        f32x4 v = *(const f32x4*)(xp + (size_t)c * NN + nq * 4);
        *(f32x4*)&tile[c][nq * 4] = v;
    }
    __syncthreads();
    unsigned short* op = xT + ((size_t)b * NN + n0) * NC + c0;
    const int nn0 = t >> 4, cq = t & 15;
    #pragma unroll
    for (int j = 0; j < 4; ++j) {
        const int nn = j * 16 + nn0;
        u16x4 o;
        #pragma unroll
        for (int ii = 0; ii < 4; ++ii) o[ii] = f2bf(tile[cq * 4 + ii][nn]);
        *(u16x4*)(op + (size_t)nn * NC + cq * 4) = o;
    }
}

// ------ K1: [phiQ;phiK^T;phiV] = phi(Wqkv @ x) ; grid = 16*6*32 -------------
// XCD chunk swizzle: XCD x gets contiguous bids = whole batches {2x,2x+1}
// so xT[b] (4 MiB) is L2-resident and re-read 6x from L2.
__global__ __launch_bounds__(256) void k_proj(
    const unsigned short* __restrict__ Wqkv, const unsigned short* __restrict__ xT,
    unsigned short* __restrict__ phiQ, unsigned short* __restrict__ phiKT,
    unsigned short* __restrict__ phiV)
{
    __shared__ char lds[32768];
    const int bid = (blockIdx.x & 7) * 384 + (blockIdx.x >> 3);  // 3072 = 8*384
    const int nt  = bid & 31;
    const int mt  = (bid >> 5) % 6;
    const int b   = bid / 192;
    const unsigned short* A  = Wqkv + mt * 128 * NC;
    const unsigned short* BT = xT + ((size_t)b * NN + nt * 128) * NC;

    const int lane = threadIdx.x & 63;
    const int w    = threadIdx.x >> 6;
    const int wr   = (w >> 1) * 64, wc = (w & 1) * 64;
    const int q4   = (lane >> 4) * 4, c15 = lane & 15;
    const int p    = mt >> 1;                 // 0=Q, 1=K, 2=V

    f32x4 acc[4][4] = {};
    if (p == 1) {
        gemm128<false>(A, NC, BT, NC, 0, 4, lds, lds + 16384, acc);
        // phiKT[n][c]: regs span c -> packed u16x4 along c
        unsigned short* dst = phiKT + (size_t)b * NN * NC;
        const int cb = (mt & 1) * 128 + wr + q4;
        const int nb = nt * 128 + wc + c15;
        #pragma unroll
        for (int m = 0; m < 4; ++m)
            #pragma unroll
            for (int n = 0; n < 4; ++n) {
                u16x4 pk;
                #pragma unroll
                for (int i = 0; i < 4; ++i) pk[i] = f2bf(phi_act(acc[m][n][i]));
                *(u16x4*)(dst + (size_t)(nb + n * 16) * NC + cb + m * 16) = pk;
            }
    } else {
        gemm128<true>(A, NC, BT, NC, 0, 4, lds, lds + 16384, acc);
        // phi{Q,V}[c][n]: SWAP -> regs span n -> packed u16x4 along n
        unsigned short* dst = (p == 0 ? phiQ : phiV) + (size_t)b * NC * NN;
        const int ob = (mt & 1) * 128 + wr + c15;   // col dim = o (c of phi)
        const int nb = nt * 128 + wc + q4;
        #pragma unroll
        for (int m = 0; m < 4; ++m)
            #pragma unroll
            for (int n = 0; n < 4; ++n) {
                u16x4 pk;
                #pragma unroll
                for (int i = 0; i < 4; ++i) pk[i] = f2bf(phi_act(acc[m][n][i]));
                *(u16x4*)(dst + (size_t)(ob + m * 16) * NN + nb + n * 16) = pk;
            }
    }
}

// ------ K2: qvT_part[s][b][d][c] partials, split-K=8 ------------------------
__global__ __launch_bounds__(256) void k_qv(
    const unsigned short* __restrict__ phiQ, const unsigned short* __restrict__ phiV,
    float* __restrict__ qvTp)
{
    __shared__ char lds[32768];
    const int bid = (blockIdx.x & 7) * 64 + (blockIdx.x >> 3);   // 512 = 8*64
    const int s = bid & 7, nt = (bid >> 3) & 1, mt = (bid >> 4) & 1, b = bid >> 5;
    const unsigned short* A  = phiQ + ((size_t)b * NC + mt * 128) * NN;
    const unsigned short* BT = phiV + ((size_t)b * NC + nt * 128) * NN;
    f32x4 acc[4][4] = {};
    gemm128<false>(A, NN, BT, NN, s * 512, 8, lds, lds + 16384, acc);

    const int lane = threadIdx.x & 63, w = threadIdx.x >> 6;
    const int wr = (w >> 1) * 64, wc = (w & 1) * 64;
    const int q4 = (lane >> 4) * 4, c15 = lane & 15;
    float* dst = qvTp + (((size_t)s * NB + b) << 16);
    const int c0 = mt * 128 + wr + q4;
    const int d0 = nt * 128 + wc + c15;
    #pragma unroll
    for (int m = 0; m < 4; ++m)
        #pragma unroll
        for (int n = 0; n < 4; ++n)
            *(f32x4*)(dst + (size_t)(d0 + n * 16) * NC + c0 + m * 16) = acc[m][n];
}

// ------ K2b: qvT[b][d][c] bf16 = sum_s partials -----------------------------
__global__ __launch_bounds__(256) void k_qvred(
    const float* __restrict__ p, unsigned short* __restrict__ qvT)
{
    const size_t i = (size_t)blockIdx.x * 256 + threadIdx.x;  // 262144 f32x4 units
    const f32x4* pv = (const f32x4*)p;
    f32x4 v = pv[i];
    #pragma unroll
    for (int s = 1; s < 8; ++s) v = v + pv[i + (size_t)s * 262144];
    u16x4 o;
    #pragma unroll
    for (int j = 0; j < 4; ++j) o[j] = f2bf(v[j]);
    ((u16x4*)qvT)[i] = o;
}

// ------ K3: Mb[b][o][d] = Wo @ qv  (SWAP: regs span d) -----------------------
__global__ __launch_bounds__(256) void k_mproj(
    const unsigned short* __restrict__ Wob, const unsigned short* __restrict__ qvT,
    unsigned short* __restrict__ Mb)
{
    __shared__ char lds[32768];
    const int bid = blockIdx.x;                    // 64 blocks
    const int nt = bid & 1, mt = (bid >> 1) & 1, b = bid >> 2;
    const unsigned short* A  = Wob + mt * 128 * NC;
    const unsigned short* BT = qvT + ((size_t)b << 16) + nt * 128 * NC;
    f32x4 acc[4][4] = {};
    gemm128<true>(A, NC, BT, NC, 0, 4, lds, lds + 16384, acc);

    const int lane = threadIdx.x & 63, w = threadIdx.x >> 6;
    const int wr = (w >> 1) * 64, wc = (w & 1) * 64;
    const int q4 = (lane >> 4) * 4, c15 = lane & 15;
    unsigned short* dst = Mb + ((size_t)b << 16);
    const int ob = mt * 128 + wr + c15;
    const int db = nt * 128 + wc + q4;
    #pragma unroll
    for (int m = 0; m < 4; ++m)
        #pragma unroll
        for (int n = 0; n < 4; ++n) {
            u16x4 pk;
            #pragma unroll
            for (int i = 0; i < 4; ++i) pk[i] = f2bf(acc[m][n][i]);
            *(u16x4*)(dst + (size_t)(ob + m * 16) * NC + db + n * 16) = pk;
        }
}

// ------ K4: out[b][o][n] = Mb @ phiK + bo  (SWAP: regs span n, f32x4 stores) -
__global__ __launch_bounds__(256) void k_out(
    const unsigned short* __restrict__ Mb, const unsigned short* __restrict__ phiKT,
    const float* __restrict__ bo, float* __restrict__ out)
{
    __shared__ char lds[32768];
    const int bid = blockIdx.x;                    // 1024 blocks
    const int nt = bid & 31, mt = (bid >> 5) & 1, b = bid >> 6;
    const unsigned short* A  = Mb + ((size_t)b << 16) + mt * 128 * NC;
    const unsigned short* BT = phiKT + (size_t)b * NN * NC + (size_t)nt * 128 * NC;
    f32x4 acc[4][4] = {};
    gemm128<true>(A, NC, BT, NC, 0, 4, lds, lds + 16384, acc);

    const int lane = threadIdx.x & 63, w = threadIdx.x >> 6;
    const int wr = (w >> 1) * 64, wc = (w & 1) * 64;
    const int q4 = (lane >> 4) * 4, c15 = lane & 15;
    float* dst = out + (size_t)b * NC * NN;
    #pragma unroll
    for (int m = 0; m < 4; ++m) {
        const int o  = mt * 128 + wr + m * 16 + c15;
        const float bb = bo[o];
        #pragma unroll
        for (int n = 0; n < 4; ++n) {
            f32x4 v = acc[m][n];
            #pragma unroll
            for (int i = 0; i < 4; ++i) v[i] += bb;
            *(f32x4*)(dst + (size_t)o * NN + nt * 128 + wc + n * 16 + q4) = v;
        }
    }
}

// ---------------------------------------------------------------------------
extern "C" void kernel_launch(void* const* d_in, const int* in_sizes, int n_in,
                              void* d_out, int out_size, void* d_ws, size_t ws_size,
                              hipStream_t stream)
{
    (void)in_sizes; (void)n_in; (void)out_size; (void)ws_size;
    const float* x  = (const float*)d_in[0];
    const float* Wq = (const float*)d_in[1];
    const float* Wk = (const float*)d_in[2];
    const float* Wv = (const float*)d_in[3];
    const float* Wo = (const float*)d_in[4];
    const float* bo = (const float*)d_in[5];
    float* out = (float*)d_out;

    char* ws = (char*)d_ws;
    size_t off = 0;
    auto alloc = [&](size_t bytes) {
        void* p = ws + off;
        off += (bytes + 255) & ~(size_t)255;
        return p;
    };
    unsigned short* xT    = (unsigned short*)alloc((size_t)NB * NN * NC * 2); // 32 MiB
    unsigned short* phiQ  = (unsigned short*)alloc((size_t)NB * NC * NN * 2); // 32 MiB
    unsigned short* phiV  = (unsigned short*)alloc((size_t)NB * NC * NN * 2); // 32 MiB
    unsigned short* phiKT = (unsigned short*)alloc((size_t)NB * NN * NC * 2); // 32 MiB
    unsigned short* qvT   = (unsigned short*)alloc((size_t)NB * NC * NC * 2); //  2 MiB
    unsigned short* Mb    = (unsigned short*)alloc((size_t)NB * NC * NC * 2); //  2 MiB
    unsigned short* Wqkv  = (unsigned short*)alloc((size_t)768 * NC * 2);
    unsigned short* Wob   = (unsigned short*)alloc((size_t)NC * NC * 2);
    float* qvTp = (float*)xT;   // alias: xT dead after k_proj; 8*16*64K*4B = 32 MiB

    k_pre<<<5120, 256, 0, stream>>>(x, Wq, Wk, Wv, Wo, xT, Wqkv, Wob);
    k_proj<<<3072, 256, 0, stream>>>(Wqkv, xT, phiQ, phiKT, phiV);
    k_qv<<<512, 256, 0, stream>>>(phiQ, phiV, qvTp);
    k_qvred<<<1024, 256, 0, stream>>>(qvTp, qvT);
    k_mproj<<<64, 256, 0, stream>>>(Wob, qvT, Mb);
    k_out<<<1024, 256, 0, stream>>>(Mb, phiKT, bo, out);
}